// Round 5
// baseline (283.808 us; speedup 1.0000x reference)
//
#include <hip/hip_runtime.h>

#define K 8

typedef float    f32x4 __attribute__((ext_vector_type(4)));
typedef int      i32x4 __attribute__((ext_vector_type(4)));
typedef unsigned u32x4 __attribute__((ext_vector_type(4)));

static __device__ __forceinline__ unsigned quant10(float v) {
    v = fminf(fmaxf(v, -1.0f), 1.0f);
    return (unsigned)__float2uint_rn((v + 1.0f) * 511.5f);   // [0,1023]
}
static __device__ __forceinline__ float dq(unsigned w, int shift) {
    const float S = 2.0f / 1023.0f;
    return (float)((w >> shift) & 1023u) * S - 1.0f;
}

// ---- pass 1: faces + vn -> per-face quantized normal table (16 B/face) ----
__global__ __launch_bounds__(256) void pack_face_normals_q10(
    const int*   __restrict__ faces,
    const float* __restrict__ vn,
    u32x4*       __restrict__ tbl,
    int F)
{
    int f = blockIdx.x * blockDim.x + threadIdx.x;
    if (f >= F) return;
    int v0 = faces[3 * f + 0];
    int v1 = faces[3 * f + 1];
    int v2 = faces[3 * f + 2];
    u32x4 r;
    r.x = quant10(vn[3 * v0 + 0]) | (quant10(vn[3 * v0 + 1]) << 10) | (quant10(vn[3 * v0 + 2]) << 20);
    r.y = quant10(vn[3 * v1 + 0]) | (quant10(vn[3 * v1 + 1]) << 10) | (quant10(vn[3 * v1 + 2]) << 20);
    r.z = quant10(vn[3 * v2 + 0]) | (quant10(vn[3 * v2 + 1]) << 10) | (quant10(vn[3 * v2 + 2]) << 20);
    r.w = 0u;
    tbl[f] = r;
}

// blend math for one pixel, everything already in registers
static __device__ __forceinline__ f32x4 blend_pixel(
    const float zk[K], const float dk[K], const int fk[K],
    const float barr[K * 3], const u32x4 rec[K])
{
    const float SIGMA_INV = 1e4f;
    const float GAMMA_INV = 1e4f;
    const float EPSV      = 1e-10f;
    const float ZFAR      = 100.0f;
    const float ZSCALE    = 1.0f / 99.0f;

    float prob[K], zinv[K], c0[K], c1[K], c2[K];
    float zmax = EPSV;
#pragma unroll
    for (int k = 0; k < K; ++k) {
        float mf = fk[k] >= 0 ? 1.0f : 0.0f;
        float p = 1.0f / (1.0f + __expf(dk[k] * SIGMA_INV));
        prob[k] = p * mf;
        zinv[k] = (ZFAR - zk[k]) * ZSCALE * mf;
        zmax = fmaxf(zmax, zinv[k]);
        unsigned w0 = rec[k].x, w1 = rec[k].y, w2 = rec[k].z;
        float b0 = barr[3 * k + 0] * mf;
        float b1 = barr[3 * k + 1] * mf;
        float b2 = barr[3 * k + 2] * mf;
        c0[k] = b0 * dq(w0, 0)  + b1 * dq(w1, 0)  + b2 * dq(w2, 0);
        c1[k] = b0 * dq(w0, 10) + b1 * dq(w1, 10) + b2 * dq(w2, 10);
        c2[k] = b0 * dq(w0, 20) + b1 * dq(w1, 20) + b2 * dq(w2, 20);
    }
    float one_minus_prod = 1.0f;
    float wsum = 0.0f, a0 = 0.0f, a1 = 0.0f, a2 = 0.0f;
#pragma unroll
    for (int k = 0; k < K; ++k) {
        one_minus_prod *= (1.0f - prob[k]);
        float w = prob[k] * __expf((zinv[k] - zmax) * GAMMA_INV);
        wsum += w;
        a0 += w * c0[k];
        a1 += w * c1[k];
        a2 += w * c2[k];
    }
    float delta = __expf((EPSV - zmax) * GAMMA_INV);
    float inv_denom = 1.0f / (wsum + delta);
    float bgw = delta * inv_denom;
    f32x4 o;
    o.x = a0 * inv_denom + bgw;
    o.y = a1 * inv_denom + bgw;
    o.z = a2 * inv_denom + bgw;
    o.w = 1.0f - one_minus_prod;
    return o;
}

// ---- pass 2: 2 pixels/thread for doubled memory-level parallelism ----
__global__ __launch_bounds__(256) void shade_blend_q10_x2(
    const float* __restrict__ bary,
    const float* __restrict__ zbuf,
    const float* __restrict__ dists,
    const int*   __restrict__ p2f,
    const u32x4* __restrict__ tbl,
    float*       __restrict__ out,
    int P, int T)          // T = total threads; pixA = tid, pixB = tid + T
{
    int tid = blockIdx.x * blockDim.x + threadIdx.x;
    if (tid >= T) return;
    int pixA = tid;
    int pixB = tid + T;
    bool hasB = pixB < P;
    int pixB_s = hasB ? pixB : pixA;   // safe address

    const i32x4* pfA = reinterpret_cast<const i32x4*>(p2f   + (size_t)pixA   * K);
    const i32x4* pfB = reinterpret_cast<const i32x4*>(p2f   + (size_t)pixB_s * K);
    const f32x4* zbA = reinterpret_cast<const f32x4*>(zbuf  + (size_t)pixA   * K);
    const f32x4* zbB = reinterpret_cast<const f32x4*>(zbuf  + (size_t)pixB_s * K);
    const f32x4* dsA = reinterpret_cast<const f32x4*>(dists + (size_t)pixA   * K);
    const f32x4* dsB = reinterpret_cast<const f32x4*>(dists + (size_t)pixB_s * K);
    const f32x4* bcA = reinterpret_cast<const f32x4*>(bary  + (size_t)pixA   * K * 3);
    const f32x4* bcB = reinterpret_cast<const f32x4*>(bary  + (size_t)pixB_s * K * 3);

    // 1) p2f first — the gather-dependency chain starts here
    i32x4 fA0 = __builtin_nontemporal_load(pfA + 0);
    i32x4 fA1 = __builtin_nontemporal_load(pfA + 1);
    i32x4 fB0 = __builtin_nontemporal_load(pfB + 0);
    i32x4 fB1 = __builtin_nontemporal_load(pfB + 1);

    // 2) streams for both pixels (independent, stay in flight)
    f32x4 zA0 = __builtin_nontemporal_load(zbA + 0);
    f32x4 zA1 = __builtin_nontemporal_load(zbA + 1);
    f32x4 dA0 = __builtin_nontemporal_load(dsA + 0);
    f32x4 dA1 = __builtin_nontemporal_load(dsA + 1);
    f32x4 zB0 = __builtin_nontemporal_load(zbB + 0);
    f32x4 zB1 = __builtin_nontemporal_load(zbB + 1);
    f32x4 dB0 = __builtin_nontemporal_load(dsB + 0);
    f32x4 dB1 = __builtin_nontemporal_load(dsB + 1);
    f32x4 bA[6], bB[6];
#pragma unroll
    for (int i = 0; i < 6; ++i) bA[i] = __builtin_nontemporal_load(bcA + i);
#pragma unroll
    for (int i = 0; i < 6; ++i) bB[i] = __builtin_nontemporal_load(bcB + i);

    int fkA[K] = { fA0.x, fA0.y, fA0.z, fA0.w, fA1.x, fA1.y, fA1.z, fA1.w };
    int fkB[K] = { fB0.x, fB0.y, fB0.z, fB0.w, fB1.x, fB1.y, fB1.z, fB1.w };

    // 3) all 16 gathers back-to-back (waits only on the 4 p2f loads)
    u32x4 recA[K], recB[K];
#pragma unroll
    for (int k = 0; k < K; ++k) {
        int fi = fkA[k] >= 0 ? fkA[k] : 0;
        recA[k] = tbl[fi];
    }
#pragma unroll
    for (int k = 0; k < K; ++k) {
        int fi = fkB[k] >= 0 ? fkB[k] : 0;
        recB[k] = tbl[fi];
    }

    // 4) compute pixel A
    {
        float zk[K] = { zA0.x, zA0.y, zA0.z, zA0.w, zA1.x, zA1.y, zA1.z, zA1.w };
        float dk[K] = { dA0.x, dA0.y, dA0.z, dA0.w, dA1.x, dA1.y, dA1.z, dA1.w };
        float barr[K * 3];
#pragma unroll
        for (int i = 0; i < 6; ++i) {
            barr[4 * i + 0] = bA[i].x; barr[4 * i + 1] = bA[i].y;
            barr[4 * i + 2] = bA[i].z; barr[4 * i + 3] = bA[i].w;
        }
        f32x4 o = blend_pixel(zk, dk, fkA, barr, recA);
        __builtin_nontemporal_store(o, reinterpret_cast<f32x4*>(out + (size_t)pixA * 4));
    }

    // 5) compute pixel B
    if (hasB) {
        float zk[K] = { zB0.x, zB0.y, zB0.z, zB0.w, zB1.x, zB1.y, zB1.z, zB1.w };
        float dk[K] = { dB0.x, dB0.y, dB0.z, dB0.w, dB1.x, dB1.y, dB1.z, dB1.w };
        float barr[K * 3];
#pragma unroll
        for (int i = 0; i < 6; ++i) {
            barr[4 * i + 0] = bB[i].x; barr[4 * i + 1] = bB[i].y;
            barr[4 * i + 2] = bB[i].z; barr[4 * i + 3] = bB[i].w;
        }
        f32x4 o = blend_pixel(zk, dk, fkB, barr, recB);
        __builtin_nontemporal_store(o, reinterpret_cast<f32x4*>(out + (size_t)pixB * 4));
    }
}

// ---- fallback (workspace too small): two-level gather, 1 px/thread ----
__global__ __launch_bounds__(256) void shade_blend_direct(
    const float* __restrict__ bary, const float* __restrict__ zbuf,
    const float* __restrict__ dists, const float* __restrict__ vn,
    const int* __restrict__ p2f, const int* __restrict__ faces,
    float* __restrict__ out, int P)
{
    const float SIGMA_INV = 1e4f, GAMMA_INV = 1e4f, EPSV = 1e-10f;
    const float ZFAR = 100.0f, ZSCALE = 1.0f / 99.0f;
    int pix = blockIdx.x * blockDim.x + threadIdx.x;
    if (pix >= P) return;
    const float4* zb4 = reinterpret_cast<const float4*>(zbuf  + (size_t)pix * K);
    const float4* ds4 = reinterpret_cast<const float4*>(dists + (size_t)pix * K);
    const int4*   pf4 = reinterpret_cast<const int4*>(p2f     + (size_t)pix * K);
    const float4* bc4 = reinterpret_cast<const float4*>(bary  + (size_t)pix * K * 3);
    float4 za = zb4[0], zb_ = zb4[1];
    float4 da = ds4[0], db_ = ds4[1];
    int4   fa = pf4[0], fb_ = pf4[1];
    float zk[K] = { za.x, za.y, za.z, za.w, zb_.x, zb_.y, zb_.z, zb_.w };
    float dk[K] = { da.x, da.y, da.z, da.w, db_.x, db_.y, db_.z, db_.w };
    int   fk[K] = { fa.x, fa.y, fa.z, fa.w, fb_.x, fb_.y, fb_.z, fb_.w };
    float barr[K * 3];
#pragma unroll
    for (int i = 0; i < 6; ++i) {
        float4 t = bc4[i];
        barr[4 * i + 0] = t.x; barr[4 * i + 1] = t.y;
        barr[4 * i + 2] = t.z; barr[4 * i + 3] = t.w;
    }
    float prob[K], zinv[K], c0[K], c1[K], c2[K];
    float zmax = EPSV;
#pragma unroll
    for (int k = 0; k < K; ++k) {
        int fraw = fk[k];
        float mf = fraw >= 0 ? 1.0f : 0.0f;
        int fi = fraw >= 0 ? fraw : 0;
        int v0 = faces[3 * fi + 0], v1 = faces[3 * fi + 1], v2 = faces[3 * fi + 2];
        float p = 1.0f / (1.0f + __expf(dk[k] * SIGMA_INV));
        prob[k] = p * mf;
        zinv[k] = (ZFAR - zk[k]) * ZSCALE * mf;
        zmax = fmaxf(zmax, zinv[k]);
        float b0 = barr[3 * k + 0] * mf, b1 = barr[3 * k + 1] * mf, b2 = barr[3 * k + 2] * mf;
        c0[k] = b0 * vn[3 * v0 + 0] + b1 * vn[3 * v1 + 0] + b2 * vn[3 * v2 + 0];
        c1[k] = b0 * vn[3 * v0 + 1] + b1 * vn[3 * v1 + 1] + b2 * vn[3 * v2 + 1];
        c2[k] = b0 * vn[3 * v0 + 2] + b1 * vn[3 * v1 + 2] + b2 * vn[3 * v2 + 2];
    }
    float one_minus_prod = 1.0f, wsum = 0.0f, a0 = 0.0f, a1 = 0.0f, a2 = 0.0f;
#pragma unroll
    for (int k = 0; k < K; ++k) {
        one_minus_prod *= (1.0f - prob[k]);
        float w = prob[k] * __expf((zinv[k] - zmax) * GAMMA_INV);
        wsum += w; a0 += w * c0[k]; a1 += w * c1[k]; a2 += w * c2[k];
    }
    float delta = __expf((EPSV - zmax) * GAMMA_INV);
    float inv_denom = 1.0f / (wsum + delta);
    float bgw = delta * inv_denom;
    float4 o;
    o.x = a0 * inv_denom + bgw; o.y = a1 * inv_denom + bgw;
    o.z = a2 * inv_denom + bgw; o.w = 1.0f - one_minus_prod;
    *reinterpret_cast<float4*>(out + (size_t)pix * 4) = o;
}

extern "C" void kernel_launch(void* const* d_in, const int* in_sizes, int n_in,
                              void* d_out, int out_size, void* d_ws, size_t ws_size,
                              hipStream_t stream) {
    const float* bary  = (const float*)d_in[0];
    const float* zbuf  = (const float*)d_in[1];
    const float* dists = (const float*)d_in[2];
    const float* vn    = (const float*)d_in[3];
    const int*   p2f   = (const int*)d_in[4];
    const int*   faces = (const int*)d_in[5];
    float* out = (float*)d_out;

    int P = out_size / 4;           // N*H*W pixels
    int F = in_sizes[5] / 3;        // faces
    int block = 256;

    size_t tbl_bytes = (size_t)F * 16;
    if (ws_size >= tbl_bytes) {
        u32x4* tbl = (u32x4*)d_ws;
        int gf = (F + block - 1) / block;
        pack_face_normals_q10<<<gf, block, 0, stream>>>(faces, vn, tbl, F);
        int T = (P + 1) / 2;
        int grid = (T + block - 1) / block;
        shade_blend_q10_x2<<<grid, block, 0, stream>>>(bary, zbuf, dists, p2f, tbl, out, P, T);
    } else {
        int grid = (P + block - 1) / block;
        shade_blend_direct<<<grid, block, 0, stream>>>(bary, zbuf, dists, vn, p2f, faces, out, P);
    }
}

// Round 6
// 250.644 us; speedup vs baseline: 1.1323x; 1.1323x over previous
//
#include <hip/hip_runtime.h>

#define K 8

typedef float    f32x4 __attribute__((ext_vector_type(4)));
typedef unsigned u32x4 __attribute__((ext_vector_type(4)));

static __device__ __forceinline__ unsigned quant10(float v) {
    v = fminf(fmaxf(v, -1.0f), 1.0f);
    return (unsigned)__float2uint_rn((v + 1.0f) * 511.5f);   // [0,1023]
}
static __device__ __forceinline__ float dq(unsigned w, int shift) {
    const float S = 2.0f / 1023.0f;
    return (float)((w >> shift) & 1023u) * S - 1.0f;
}

// ---- pass 1: faces + vn -> per-face quantized normal table (16 B/face) ----
__global__ __launch_bounds__(256) void pack_face_normals_q10(
    const int*   __restrict__ faces,
    const float* __restrict__ vn,
    u32x4*       __restrict__ tbl,
    int F)
{
    int f = blockIdx.x * blockDim.x + threadIdx.x;
    if (f >= F) return;
    int v0 = faces[3 * f + 0];
    int v1 = faces[3 * f + 1];
    int v2 = faces[3 * f + 2];
    u32x4 r;
    r.x = quant10(vn[3 * v0 + 0]) | (quant10(vn[3 * v0 + 1]) << 10) | (quant10(vn[3 * v0 + 2]) << 20);
    r.y = quant10(vn[3 * v1 + 0]) | (quant10(vn[3 * v1 + 1]) << 10) | (quant10(vn[3 * v1 + 2]) << 20);
    r.z = quant10(vn[3 * v2 + 0]) | (quant10(vn[3 * v2 + 1]) << 10) | (quant10(vn[3 * v2 + 2]) << 20);
    r.w = 0u;
    tbl[f] = r;
}

// ---- pass 2: one thread per FRAGMENT; 8-lane shfl_xor reduce per pixel ----
__global__ __launch_bounds__(256) void shade_blend_frag(
    const float* __restrict__ bary,   // [P,K,3]
    const float* __restrict__ zbuf,   // [P,K]
    const float* __restrict__ dists,  // [P,K]
    const int*   __restrict__ p2f,    // [P,K]
    const u32x4* __restrict__ tbl,    // [F]
    float*       __restrict__ out,    // [P,4]
    int total)                        // P*K
{
    const float SIGMA_INV = 1e4f;
    const float GAMMA_INV = 1e4f;
    const float EPSV      = 1e-10f;
    const float ZFAR      = 100.0f;
    const float ZSCALE    = 1.0f / 99.0f;

    int tid = blockIdx.x * blockDim.x + threadIdx.x;
    if (tid >= total) return;
    int pix = tid >> 3;
    int k   = tid & 7;

    // coalesced streaming loads (lane-linear addresses)
    int   f = __builtin_nontemporal_load(p2f   + tid);
    float z = __builtin_nontemporal_load(zbuf  + tid);
    float d = __builtin_nontemporal_load(dists + tid);
    const float* bb = bary + (size_t)tid * 3;
    float b0 = __builtin_nontemporal_load(bb + 0);
    float b1 = __builtin_nontemporal_load(bb + 1);
    float b2 = __builtin_nontemporal_load(bb + 2);

    // single 16 B gather per fragment
    int fi = f >= 0 ? f : 0;
    u32x4 rec = tbl[fi];
    float mf = f >= 0 ? 1.0f : 0.0f;

    float p    = 1.0f / (1.0f + __expf(d * SIGMA_INV));
    float prob = p * mf;
    float zinv = (ZFAR - z) * ZSCALE * mf;
    b0 *= mf; b1 *= mf; b2 *= mf;
    float c0 = b0 * dq(rec.x, 0)  + b1 * dq(rec.y, 0)  + b2 * dq(rec.z, 0);
    float c1 = b0 * dq(rec.x, 10) + b1 * dq(rec.y, 10) + b2 * dq(rec.z, 10);
    float c2 = b0 * dq(rec.x, 20) + b1 * dq(rec.y, 20) + b2 * dq(rec.z, 20);

    // group max over the pixel's 8 fragments (lanes differ only in bits 0..2)
    float zmax = fmaxf(zinv, EPSV);
    zmax = fmaxf(zmax, __shfl_xor(zmax, 1));
    zmax = fmaxf(zmax, __shfl_xor(zmax, 2));
    zmax = fmaxf(zmax, __shfl_xor(zmax, 4));

    float w  = prob * __expf((zinv - zmax) * GAMMA_INV);
    float a0 = w * c0, a1 = w * c1, a2 = w * c2;
    float pm = 1.0f - prob;

#pragma unroll
    for (int m = 1; m <= 4; m <<= 1) {
        w  += __shfl_xor(w,  m);
        a0 += __shfl_xor(a0, m);
        a1 += __shfl_xor(a1, m);
        a2 += __shfl_xor(a2, m);
        pm *= __shfl_xor(pm, m);
    }

    float delta = __expf((EPSV - zmax) * GAMMA_INV);
    float invd  = 1.0f / (w + delta);
    float bgw   = delta * invd;        // background = (1,1,1)

    if (k < 4) {
        float val = (k == 0) ? a0 * invd + bgw
                  : (k == 1) ? a1 * invd + bgw
                  : (k == 2) ? a2 * invd + bgw
                  :            1.0f - pm;
        __builtin_nontemporal_store(val, out + (size_t)pix * 4 + k);
    }
}

// ---- fallback (workspace too small): two-level gather, 1 px/thread ----
__global__ __launch_bounds__(256) void shade_blend_direct(
    const float* __restrict__ bary, const float* __restrict__ zbuf,
    const float* __restrict__ dists, const float* __restrict__ vn,
    const int* __restrict__ p2f, const int* __restrict__ faces,
    float* __restrict__ out, int P)
{
    const float SIGMA_INV = 1e4f, GAMMA_INV = 1e4f, EPSV = 1e-10f;
    const float ZFAR = 100.0f, ZSCALE = 1.0f / 99.0f;
    int pix = blockIdx.x * blockDim.x + threadIdx.x;
    if (pix >= P) return;
    const float4* zb4 = reinterpret_cast<const float4*>(zbuf  + (size_t)pix * K);
    const float4* ds4 = reinterpret_cast<const float4*>(dists + (size_t)pix * K);
    const int4*   pf4 = reinterpret_cast<const int4*>(p2f     + (size_t)pix * K);
    const float4* bc4 = reinterpret_cast<const float4*>(bary  + (size_t)pix * K * 3);
    float4 za = zb4[0], zb_ = zb4[1];
    float4 da = ds4[0], db_ = ds4[1];
    int4   fa = pf4[0], fb_ = pf4[1];
    float zk[K] = { za.x, za.y, za.z, za.w, zb_.x, zb_.y, zb_.z, zb_.w };
    float dk[K] = { da.x, da.y, da.z, da.w, db_.x, db_.y, db_.z, db_.w };
    int   fk[K] = { fa.x, fa.y, fa.z, fa.w, fb_.x, fb_.y, fb_.z, fb_.w };
    float barr[K * 3];
#pragma unroll
    for (int i = 0; i < 6; ++i) {
        float4 t = bc4[i];
        barr[4 * i + 0] = t.x; barr[4 * i + 1] = t.y;
        barr[4 * i + 2] = t.z; barr[4 * i + 3] = t.w;
    }
    float prob[K], zinv[K], c0[K], c1[K], c2[K];
    float zmax = EPSV;
#pragma unroll
    for (int kk = 0; kk < K; ++kk) {
        int fraw = fk[kk];
        float mf = fraw >= 0 ? 1.0f : 0.0f;
        int fi = fraw >= 0 ? fraw : 0;
        int v0 = faces[3 * fi + 0], v1 = faces[3 * fi + 1], v2 = faces[3 * fi + 2];
        float p = 1.0f / (1.0f + __expf(dk[kk] * SIGMA_INV));
        prob[kk] = p * mf;
        zinv[kk] = (ZFAR - zk[kk]) * ZSCALE * mf;
        zmax = fmaxf(zmax, zinv[kk]);
        float b0 = barr[3 * kk + 0] * mf, b1 = barr[3 * kk + 1] * mf, b2 = barr[3 * kk + 2] * mf;
        c0[kk] = b0 * vn[3 * v0 + 0] + b1 * vn[3 * v1 + 0] + b2 * vn[3 * v2 + 0];
        c1[kk] = b0 * vn[3 * v0 + 1] + b1 * vn[3 * v1 + 1] + b2 * vn[3 * v2 + 1];
        c2[kk] = b0 * vn[3 * v0 + 2] + b1 * vn[3 * v1 + 2] + b2 * vn[3 * v2 + 2];
    }
    float one_minus_prod = 1.0f, wsum = 0.0f, a0 = 0.0f, a1 = 0.0f, a2 = 0.0f;
#pragma unroll
    for (int kk = 0; kk < K; ++kk) {
        one_minus_prod *= (1.0f - prob[kk]);
        float w = prob[kk] * __expf((zinv[kk] - zmax) * GAMMA_INV);
        wsum += w; a0 += w * c0[kk]; a1 += w * c1[kk]; a2 += w * c2[kk];
    }
    float delta = __expf((EPSV - zmax) * GAMMA_INV);
    float inv_denom = 1.0f / (wsum + delta);
    float bgw = delta * inv_denom;
    float4 o;
    o.x = a0 * inv_denom + bgw; o.y = a1 * inv_denom + bgw;
    o.z = a2 * inv_denom + bgw; o.w = 1.0f - one_minus_prod;
    *reinterpret_cast<float4*>(out + (size_t)pix * 4) = o;
}

extern "C" void kernel_launch(void* const* d_in, const int* in_sizes, int n_in,
                              void* d_out, int out_size, void* d_ws, size_t ws_size,
                              hipStream_t stream) {
    const float* bary  = (const float*)d_in[0];
    const float* zbuf  = (const float*)d_in[1];
    const float* dists = (const float*)d_in[2];
    const float* vn    = (const float*)d_in[3];
    const int*   p2f   = (const int*)d_in[4];
    const int*   faces = (const int*)d_in[5];
    float* out = (float*)d_out;

    int P = out_size / 4;           // N*H*W pixels
    int F = in_sizes[5] / 3;        // faces
    int block = 256;

    size_t tbl_bytes = (size_t)F * 16;
    if (ws_size >= tbl_bytes) {
        u32x4* tbl = (u32x4*)d_ws;
        int gf = (F + block - 1) / block;
        pack_face_normals_q10<<<gf, block, 0, stream>>>(faces, vn, tbl, F);
        int total = P * K;
        int grid = (total + block - 1) / block;
        shade_blend_frag<<<grid, block, 0, stream>>>(bary, zbuf, dists, p2f, tbl, out, total);
    } else {
        int grid = (P + block - 1) / block;
        shade_blend_direct<<<grid, block, 0, stream>>>(bary, zbuf, dists, vn, p2f, faces, out, P);
    }
}